// Round 12
// baseline (395.037 us; speedup 1.0000x reference)
//
#include <hip/hip_runtime.h>
#include <hip/hip_bf16.h>

#define NN 6144
#define DD 128
#define PBL 136         // padded LDS row stride (bf16 elems) -> balanced banks
#define INV_TAU 10.0f

typedef __attribute__((ext_vector_type(4))) float f32x4;
typedef __attribute__((ext_vector_type(8))) short s16x8;

// Force a real in-flight global load: volatile asm cannot be sunk or
// serialized by the register allocator (R7/R8/R10/R11 evidence: every
// compiler-visible batching attempt ended at VGPR<=24 + serial round-trips).
__device__ __forceinline__ void ld4_async(const float4* p, float4& d) {
    asm volatile("global_load_dwordx4 %0, %1, off" : "=v"(d) : "v"(p));
}
__device__ __forceinline__ void vm_wait0() {
    asm volatile("s_waitcnt vmcnt(0)" ::: "memory");
}

// ---------------- Kernel 1: L2 normalize -> fp32 Fn, bf16 copies, inv-norms
__global__ void k_normalize(const float* __restrict__ embF,
                            const float* __restrict__ embM,
                            const float* __restrict__ embP,
                            float* __restrict__ Fn,
                            float* __restrict__ rnM, float* __restrict__ rnP,
                            __hip_bfloat16* __restrict__ Fnb,
                            __hip_bfloat16* __restrict__ Mnb,
                            __hip_bfloat16* __restrict__ Pnb) {
    int which = blockIdx.y;
    const float* src = which == 0 ? embF : (which == 1 ? embM : embP);
    __hip_bfloat16* dstb = which == 0 ? Fnb : (which == 1 ? Mnb : Pnb);
    int wave = threadIdx.x >> 6, lane = threadIdx.x & 63;
    int row = blockIdx.x * 4 + wave;
    float2 v = reinterpret_cast<const float2*>(src + (size_t)row * DD)[lane];
    float s = v.x * v.x + v.y * v.y;
#pragma unroll
    for (int m = 1; m <= 32; m <<= 1) s += __shfl_xor(s, m);
    float inv = 1.0f / fmaxf(sqrtf(s), 1e-12f);
    float2 o; o.x = v.x * inv; o.y = v.y * inv;
    if (which == 0)
        reinterpret_cast<float2*>(Fn + (size_t)row * DD)[lane] = o;
    if (lane == 0) {
        if (which == 1) rnM[row] = inv;
        if (which == 2) rnP[row] = inv;
    }
    __hip_bfloat162 ob;
    ob.x = __float2bfloat16(o.x);
    ob.y = __float2bfloat16(o.y);
    reinterpret_cast<__hip_bfloat162*>(dstb + (size_t)row * DD)[lane] = ob;
}

// ------- Kernel 2: fused scan + gather, one block per (row, half) ----------
__global__ __launch_bounds__(256) void k_sparse2(
        const float* __restrict__ FM_adj, const float* __restrict__ FP_adj,
        const float* __restrict__ embM, const float* __restrict__ embP,
        const float* __restrict__ Fn,
        const float* __restrict__ rnM, const float* __restrict__ rnP,
        float* __restrict__ feat,
        float* __restrict__ FMpos, float* __restrict__ FPpos,
        float* __restrict__ cntF, float* __restrict__ cntP) {
    __shared__ float FnS[DD];
    __shared__ int lbufT[256][4];            // 4 KB per-thread side buffers
    __shared__ int listS[128];
    __shared__ float reprS[8][DD];           // 4 KB half-wave partials
    __shared__ float posS[8];
    __shared__ int wvS[4];
    __shared__ int Ktot[2];                  // [0] capped K, [1] true total
    const int row = blockIdx.x, h = blockIdx.y;
    const float* adj  = h ? FP_adj : FM_adj;
    const float* embX = h ? embP : embM;
    const float* RN   = h ? rnP : rnM;
    const int tid = threadIdx.x, wv = tid >> 6, lane = tid & 63;

    if (tid < 32)
        reinterpret_cast<float4*>(FnS)[tid] =
            reinterpret_cast<const float4*>(Fn + (size_t)row * DD)[tid];

    // ---- phase A: scan with 6 asm-forced loads in flight ----
    const float4* rp = reinterpret_cast<const float4*>(adj + (size_t)row * NN);
    float4 v0, v1, v2, v3, v4, v5;
    ld4_async(rp + tid,        v0);
    ld4_async(rp + 256 + tid,  v1);
    ld4_async(rp + 512 + tid,  v2);
    ld4_async(rp + 768 + tid,  v3);
    ld4_async(rp + 1024 + tid, v4);
    ld4_async(rp + 1280 + tid, v5);
    vm_wait0();
    float4 vv[6] = {v0, v1, v2, v3, v4, v5};
    int mycnt = 0;
#pragma unroll
    for (int u = 0; u < 6; ++u) {
        int cb = (u * 256 + tid) * 4;
        if (vv[u].x != 0.f) { if (mycnt < 4) lbufT[tid][mycnt] = cb;     mycnt++; }
        if (vv[u].y != 0.f) { if (mycnt < 4) lbufT[tid][mycnt] = cb + 1; mycnt++; }
        if (vv[u].z != 0.f) { if (mycnt < 4) lbufT[tid][mycnt] = cb + 2; mycnt++; }
        if (vv[u].w != 0.f) { if (mycnt < 4) lbufT[tid][mycnt] = cb + 3; mycnt++; }
    }
    int cnt = mycnt < 4 ? mycnt : 4;         // P(thread>4 nnz in 24 cols) ~ 0
    int x = cnt;                             // inclusive prefix within wave
#pragma unroll
    for (int d = 1; d < 64; d <<= 1) {
        int y = __shfl_up(x, d);
        if (lane >= d) x += y;
    }
    int t = mycnt;                           // true per-wave total
#pragma unroll
    for (int msk = 1; msk <= 32; msk <<= 1) t += __shfl_xor(t, msk);
    if (tid == 0) Ktot[1] = 0;
    if (lane == 63) wvS[wv] = x;
    __syncthreads();
    if (lane == 0) atomicAdd(&Ktot[1], t);
    if (tid == 0) {
        int s = 0;
#pragma unroll
        for (int i = 0; i < 4; ++i) { int v = wvS[i]; wvS[i] = s; s += v; }
        Ktot[0] = s < 128 ? s : 128;
    }
    __syncthreads();
    int off = wvS[wv] + (x - cnt);
    for (int i = 0; i < cnt; ++i) {
        int s = off + i;
        if (s < 128) listS[s] = lbufT[tid][i];
    }
    __syncthreads();
    const int K = Ktot[0];
    const float trueK = (float)Ktot[1];

    // ---- phase B: gather (half-wave per neighbor) ----
    const int hw = tid >> 5, sl = tid & 31;
    float4 f4 = reinterpret_cast<const float4*>(FnS)[sl];
    float4 racc = {0.f, 0.f, 0.f, 0.f};
    float wsum = 0.f;
    for (int k = hw; k < K; k += 8) {
        int j = listS[k];
        float rn = RN[j];
        float4 e = reinterpret_cast<const float4*>(embX + (size_t)j * DD)[sl];
        racc.x += e.x; racc.y += e.y; racc.z += e.z; racc.w += e.w;
        float d = f4.x * e.x + f4.y * e.y + f4.z * e.z + f4.w * e.w;
#pragma unroll
        for (int msk = 1; msk <= 16; msk <<= 1) d += __shfl_xor(d, msk);
        wsum += __expf(d * rn * INV_TAU);
    }
    reinterpret_cast<float4*>(&reprS[hw][0])[sl] = racc;
    if (sl == 0) posS[hw] = wsum;
    __syncthreads();
    if (tid < DD) {
        float s = 0.f;
#pragma unroll
        for (int i = 0; i < 8; ++i) s += reprS[i][tid];
        feat[(size_t)row * (2 * DD) + h * DD + tid] = s / fmaxf(trueK, 1.0f);
    }
    if (tid == 0) {
        float p = 0.f;
#pragma unroll
        for (int i = 0; i < 8; ++i) p += posS[i];
        (h ? FPpos : FMpos)[row] = p;
        (h ? cntP : cntF)[row] = trueK;
    }
}

// ------- Kernel 3: dense exp row-sum, 64-col LDS tiles, asm prefetch -------
// grid (48, 16, 2), block 256 = 4 waves; wave owns 32 rows (2 frag groups).
// 6 iters x 64 cols; staging loads issued via asm right after barrier B,
// waitcnt only at next iteration top -> in flight across all MFMA+exp.
__global__ __launch_bounds__(256) void k_dense(
        const __hip_bfloat16* __restrict__ Fnb,
        const __hip_bfloat16* __restrict__ Mnb,
        const __hip_bfloat16* __restrict__ Pnb,
        float* __restrict__ FMtot, float* __restrict__ FPtot) {
    __shared__ __hip_bfloat16 Bs[64][PBL];           // 17408 B
    const int half = blockIdx.z;
    const __hip_bfloat16* Bnb = half ? Pnb : Mnb;
    float* TOT = half ? FPtot : FMtot;
    const int tid = threadIdx.x;
    const int w = tid >> 6, lane = tid & 63;
    const int m = lane & 15, q = lane >> 4;
    const int rb = blockIdx.x * 128 + w * 32;
    const int j0 = blockIdx.y * (NN / 16);           // 384-col strip

    s16x8 a[2][4];
#pragma unroll
    for (int g = 0; g < 2; ++g)
#pragma unroll
        for (int ks = 0; ks < 4; ++ks)
            a[g][ks] = *reinterpret_cast<const s16x8*>(
                Fnb + (size_t)(rb + g * 16 + m) * DD + ks * 32 + q * 8);

    // staging slots: 1024 float4 = 64 rows x 16 float4
    float4 s0, s1, s2, s3;
    auto issue = [&](int jc) {
        const float4* gp = reinterpret_cast<const float4*>(Bnb + (size_t)jc * DD);
        ld4_async(gp + tid,       s0);
        ld4_async(gp + 256 + tid, s1);
        ld4_async(gp + 512 + tid, s2);
        ld4_async(gp + 768 + tid, s3);
    };
    auto stash = [&](int idx, const float4& v) {
        *reinterpret_cast<float4*>(&Bs[idx >> 4][(idx & 15) * 8]) = v;
    };

    issue(j0);
    float tot[2][4] = {{0.f, 0.f, 0.f, 0.f}, {0.f, 0.f, 0.f, 0.f}};
    for (int it = 0; it < 6; ++it) {
        vm_wait0();                      // staged data in regs
        __syncthreads();                 // previous tile fully consumed
        stash(tid, s0);
        stash(256 + tid, s1);
        stash(512 + tid, s2);
        stash(768 + tid, s3);
        __syncthreads();                 // tile visible to all waves
        if (it + 1 < 6) issue(j0 + (it + 1) * 64);
#pragma unroll
        for (int t = 0; t < 4; ++t) {
            s16x8 b[4];
#pragma unroll
            for (int ks = 0; ks < 4; ++ks)
                b[ks] = *reinterpret_cast<const s16x8*>(
                    &Bs[t * 16 + m][ks * 32 + q * 8]);
#pragma unroll
            for (int g = 0; g < 2; ++g) {
                f32x4 acc = {0.f, 0.f, 0.f, 0.f};
#pragma unroll
                for (int ks = 0; ks < 4; ++ks)
                    acc = __builtin_amdgcn_mfma_f32_16x16x32_bf16(
                        a[g][ks], b[ks], acc, 0, 0, 0);
#pragma unroll
                for (int r = 0; r < 4; ++r)
                    tot[g][r] += __expf(acc[r] * INV_TAU);
            }
        }
    }
#pragma unroll
    for (int msk = 1; msk <= 8; msk <<= 1)
#pragma unroll
        for (int g = 0; g < 2; ++g)
#pragma unroll
            for (int r = 0; r < 4; ++r)
                tot[g][r] += __shfl_xor(tot[g][r], msk);
    if (m == 0)
#pragma unroll
        for (int g = 0; g < 2; ++g)
#pragma unroll
            for (int r = 0; r < 4; ++r)
                atomicAdd(&TOT[rb + g * 16 + q * 4 + r], tot[g][r]);
}

// ------- Kernel 4: MLP + softmax + loss (4 rows / 256-thread block) --------
__global__ __launch_bounds__(256) void k_mlp(
        const float* __restrict__ feat,
        const float* __restrict__ W1, const float* __restrict__ b1,
        const float* __restrict__ W2, const float* __restrict__ b2,
        const float* __restrict__ FMpos, const float* __restrict__ FPpos,
        const float* __restrict__ FMtot, const float* __restrict__ FPtot,
        const float* __restrict__ cntF, const float* __restrict__ cntP,
        float* __restrict__ out) {
    __shared__ float featS[4][2 * DD];               // 4 KB
    __shared__ float partS[2][4][DD];                // 4 KB
    __shared__ float redS[2][4][2];
    __shared__ float lossS[4];
    const int tid = threadIdx.x;
    const int cp = tid >> 7, d = tid & 127;
    const int row0 = blockIdx.x * 4;
    for (int idx = tid; idx < 4 * 2 * DD; idx += 256)
        featS[idx >> 8][idx & 255] = feat[(size_t)row0 * (2 * DD) + idx];
    __syncthreads();
    float bb = (cp == 0) ? b1[d] : 0.f;
    float acc[4];
#pragma unroll
    for (int r = 0; r < 4; ++r) acc[r] = bb;
    const int c0 = cp * 128;
    for (int c = c0; c < c0 + 128; c += 2) {
        float wA = W1[c * DD + d];
        float wB = W1[(c + 1) * DD + d];
#pragma unroll
        for (int r = 0; r < 4; ++r)
            acc[r] = fmaf(featS[r][c + 1], wB, fmaf(featS[r][c], wA, acc[r]));
    }
#pragma unroll
    for (int r = 0; r < 4; ++r) partS[cp][r][d] = acc[r];
    __syncthreads();
    if (tid < 128) {
        const int lane = tid & 63, wv = tid >> 6;
        float w20 = W2[2 * tid], w21 = W2[2 * tid + 1];
        float p0s[4], p1s[4];
#pragma unroll
        for (int r = 0; r < 4; ++r) {
            float hh = fmaxf(partS[0][r][tid] + partS[1][r][tid], 0.f);
            p0s[r] = hh * w20;
            p1s[r] = hh * w21;
        }
#pragma unroll
        for (int r = 0; r < 4; ++r)
#pragma unroll
            for (int msk = 1; msk <= 32; msk <<= 1) {
                p0s[r] += __shfl_xor(p0s[r], msk);
                p1s[r] += __shfl_xor(p1s[r], msk);
            }
        if (lane == 0)
#pragma unroll
            for (int r = 0; r < 4; ++r) {
                redS[wv][r][0] = p0s[r];
                redS[wv][r][1] = p1s[r];
            }
    }
    __syncthreads();
    if (tid < 4) {
        int row = row0 + tid;
        float z0 = redS[0][tid][0] + redS[1][tid][0] + b2[0];
        float z1 = redS[0][tid][1] + redS[1][tid][1] + b2[1];
        float mx = fmaxf(z0, z1);
        float e0 = expf(z0 - mx), e1 = expf(z1 - mx);
        float inv = 1.0f / (e0 + e1);
        float w0 = e0 * inv, w1 = e1 * inv;
        out[1 + row * 2 + 0] = w0;
        out[1 + row * 2 + 1] = w1;
        float wp = w0 * FMpos[row] + w1 * FPpos[row];
        float wn = w0 * (FMtot[row] - FMpos[row]) +
                   w1 * (FPtot[row] - FPpos[row]);
        float nei = fmaxf(cntF[row] + cntP[row], 1.0f);
        float ratio = wp / (wp + wn) / nei;
        ratio = fmaxf(ratio, 1e-10f);
        lossS[tid] = -logf(ratio);
    }
    __syncthreads();
    if (tid == 0) {
        float L = 0.f;
#pragma unroll
        for (int r = 0; r < 4; ++r) L += lossS[r];
        atomicAdd(out, L * (1.0f / NN));
    }
}

extern "C" void kernel_launch(void* const* d_in, const int* in_sizes, int n_in,
                              void* d_out, int out_size, void* d_ws, size_t ws_size,
                              hipStream_t stream) {
    const float* embF   = (const float*)d_in[0];
    const float* embM   = (const float*)d_in[1];
    const float* embP   = (const float*)d_in[2];
    const float* FM_adj = (const float*)d_in[3];
    const float* FP_adj = (const float*)d_in[4];
    const float* W1     = (const float*)d_in[5];
    const float* b1     = (const float*)d_in[6];
    const float* W2     = (const float*)d_in[7];
    const float* b2     = (const float*)d_in[8];
    float* out = (float*)d_out;

    float* ws = (float*)d_ws;
    float* FMtot = ws;                       // N  (atomic -> zeroed)
    float* FPtot = FMtot + NN;               // N  (atomic -> zeroed)
    float* FMpos = FPtot + NN;               // N
    float* FPpos = FMpos + NN;               // N
    float* cntF  = FPpos + NN;               // N
    float* cntP  = cntF + NN;                // N
    float* rnM   = cntP + NN;                // N
    float* rnP   = rnM + NN;                 // N
    float* feat  = rnP + NN;                 // N*2D
    float* Fn    = feat + (size_t)NN * 2 * DD;   // N*D fp32 normalized
    __hip_bfloat16* Fnb = (__hip_bfloat16*)(Fn + (size_t)NN * DD);
    __hip_bfloat16* Mnb = Fnb + (size_t)NN * DD;
    __hip_bfloat16* Pnb = Mnb + (size_t)NN * DD;

    hipMemsetAsync(FMtot, 0, 2 * NN * sizeof(float), stream);
    hipMemsetAsync(d_out, 0, sizeof(float), stream);

    k_normalize<<<dim3(NN / 4, 3), 256, 0, stream>>>(embF, embM, embP,
                                                     Fn, rnM, rnP,
                                                     Fnb, Mnb, Pnb);
    k_sparse2<<<dim3(NN, 2), 256, 0, stream>>>(FM_adj, FP_adj, embM, embP,
                                               Fn, rnM, rnP, feat,
                                               FMpos, FPpos, cntF, cntP);
    k_dense<<<dim3(NN / 128, 16, 2), 256, 0, stream>>>(Fnb, Mnb, Pnb,
                                                       FMtot, FPtot);
    k_mlp<<<dim3(NN / 4), 256, 0, stream>>>(feat, W1, b1, W2, b2,
                                            FMpos, FPpos, FMtot, FPtot,
                                            cntF, cntP, out);
}

// Round 13
// 384.241 us; speedup vs baseline: 1.0281x; 1.0281x over previous
//
#include <hip/hip_runtime.h>
#include <hip/hip_bf16.h>

#define NN 6144
#define DD 128
#define PBL 136         // padded LDS row stride (bf16 elems) -> balanced banks
#define INV_TAU 10.0f

typedef __attribute__((ext_vector_type(4))) float f32x4;
typedef __attribute__((ext_vector_type(8))) short s16x8;

__device__ __forceinline__ void ld4_async(const float4* p, float4& d) {
    asm volatile("global_load_dwordx4 %0, %1, off" : "=v"(d) : "v"(p));
}
__device__ __forceinline__ void vm_wait0() {
    asm volatile("s_waitcnt vmcnt(0)" ::: "memory");
}

// ---------------- Kernel 1: L2 normalize -> fp32 Fn, bf16 copies, inv-norms
__global__ void k_normalize(const float* __restrict__ embF,
                            const float* __restrict__ embM,
                            const float* __restrict__ embP,
                            float* __restrict__ Fn,
                            float* __restrict__ rnM, float* __restrict__ rnP,
                            __hip_bfloat16* __restrict__ Fnb,
                            __hip_bfloat16* __restrict__ Mnb,
                            __hip_bfloat16* __restrict__ Pnb) {
    int which = blockIdx.y;
    const float* src = which == 0 ? embF : (which == 1 ? embM : embP);
    __hip_bfloat16* dstb = which == 0 ? Fnb : (which == 1 ? Mnb : Pnb);
    int wave = threadIdx.x >> 6, lane = threadIdx.x & 63;
    int row = blockIdx.x * 4 + wave;
    float2 v = reinterpret_cast<const float2*>(src + (size_t)row * DD)[lane];
    float s = v.x * v.x + v.y * v.y;
#pragma unroll
    for (int m = 1; m <= 32; m <<= 1) s += __shfl_xor(s, m);
    float inv = 1.0f / fmaxf(sqrtf(s), 1e-12f);
    float2 o; o.x = v.x * inv; o.y = v.y * inv;
    if (which == 0)
        reinterpret_cast<float2*>(Fn + (size_t)row * DD)[lane] = o;
    if (lane == 0) {
        if (which == 1) rnM[row] = inv;
        if (which == 2) rnP[row] = inv;
    }
    __hip_bfloat162 ob;
    ob.x = __float2bfloat16(o.x);
    ob.y = __float2bfloat16(o.y);
    reinterpret_cast<__hip_bfloat162*>(dstb + (size_t)row * DD)[lane] = ob;
}

// ---------- sparse body: fused scan + gather for one (row, half) -----------
__device__ __forceinline__ void sparse_body(
        int unit, char* smem,
        const float* __restrict__ FM_adj, const float* __restrict__ FP_adj,
        const float* __restrict__ embM, const float* __restrict__ embP,
        const float* __restrict__ Fn,
        const float* __restrict__ rnM, const float* __restrict__ rnP,
        float* __restrict__ feat,
        float* __restrict__ FMpos, float* __restrict__ FPpos,
        float* __restrict__ cntF, float* __restrict__ cntP) {
    float* FnS = (float*)smem;                         // 128 f
    int (*lbufT)[4] = (int(*)[4])(smem + 512);         // 256x4 i
    int* listS = (int*)(smem + 512 + 4096);            // 128 i
    float (*reprS)[DD] = (float(*)[DD])(smem + 512 + 4096 + 512);  // 8x128 f
    float* posS = (float*)(smem + 512 + 4096 + 512 + 4096);        // 8 f
    int* wvS = (int*)(smem + 512 + 4096 + 512 + 4096 + 32);        // 4 i
    int* Ktot = (int*)(smem + 512 + 4096 + 512 + 4096 + 32 + 16);  // 2 i

    const int row = unit >> 1, h = unit & 1;
    const float* adj  = h ? FP_adj : FM_adj;
    const float* embX = h ? embP : embM;
    const float* RN   = h ? rnP : rnM;
    const int tid = threadIdx.x, wv = tid >> 6, lane = tid & 63;

    if (tid < 32)
        reinterpret_cast<float4*>(FnS)[tid] =
            reinterpret_cast<const float4*>(Fn + (size_t)row * DD)[tid];

    // ---- phase A: scan with 6 asm-forced loads in flight ----
    const float4* rp = reinterpret_cast<const float4*>(adj + (size_t)row * NN);
    float4 v0, v1, v2, v3, v4, v5;
    ld4_async(rp + tid,        v0);
    ld4_async(rp + 256 + tid,  v1);
    ld4_async(rp + 512 + tid,  v2);
    ld4_async(rp + 768 + tid,  v3);
    ld4_async(rp + 1024 + tid, v4);
    ld4_async(rp + 1280 + tid, v5);
    vm_wait0();
    float4 vv[6] = {v0, v1, v2, v3, v4, v5};
    int mycnt = 0;
#pragma unroll
    for (int u = 0; u < 6; ++u) {
        int cb = (u * 256 + tid) * 4;
        if (vv[u].x != 0.f) { if (mycnt < 4) lbufT[tid][mycnt] = cb;     mycnt++; }
        if (vv[u].y != 0.f) { if (mycnt < 4) lbufT[tid][mycnt] = cb + 1; mycnt++; }
        if (vv[u].z != 0.f) { if (mycnt < 4) lbufT[tid][mycnt] = cb + 2; mycnt++; }
        if (vv[u].w != 0.f) { if (mycnt < 4) lbufT[tid][mycnt] = cb + 3; mycnt++; }
    }
    int cnt = mycnt < 4 ? mycnt : 4;         // P(thread>4 nnz in 24 cols) ~ 0
    int x = cnt;                             // inclusive prefix within wave
#pragma unroll
    for (int d = 1; d < 64; d <<= 1) {
        int y = __shfl_up(x, d);
        if (lane >= d) x += y;
    }
    int t = mycnt;                           // true per-wave total
#pragma unroll
    for (int msk = 1; msk <= 32; msk <<= 1) t += __shfl_xor(t, msk);
    if (tid == 0) Ktot[1] = 0;
    if (lane == 63) wvS[wv] = x;
    __syncthreads();
    if (lane == 0) atomicAdd(&Ktot[1], t);
    if (tid == 0) {
        int s = 0;
#pragma unroll
        for (int i = 0; i < 4; ++i) { int v = wvS[i]; wvS[i] = s; s += v; }
        Ktot[0] = s < 128 ? s : 128;
    }
    __syncthreads();
    int off = wvS[wv] + (x - cnt);
    for (int i = 0; i < cnt; ++i) {
        int s = off + i;
        if (s < 128) listS[s] = lbufT[tid][i];
    }
    __syncthreads();
    const int K = Ktot[0];
    const float trueK = (float)Ktot[1];

    // ---- phase B: gather (half-wave per neighbor) ----
    const int hw = tid >> 5, sl = tid & 31;
    float4 f4 = reinterpret_cast<const float4*>(FnS)[sl];
    float4 racc = {0.f, 0.f, 0.f, 0.f};
    float wsum = 0.f;
    for (int k = hw; k < K; k += 8) {
        int j = listS[k];
        float rn = RN[j];
        float4 e = reinterpret_cast<const float4*>(embX + (size_t)j * DD)[sl];
        racc.x += e.x; racc.y += e.y; racc.z += e.z; racc.w += e.w;
        float d = f4.x * e.x + f4.y * e.y + f4.z * e.z + f4.w * e.w;
#pragma unroll
        for (int msk = 1; msk <= 16; msk <<= 1) d += __shfl_xor(d, msk);
        wsum += __expf(d * rn * INV_TAU);
    }
    reinterpret_cast<float4*>(&reprS[hw][0])[sl] = racc;
    if (sl == 0) posS[hw] = wsum;
    __syncthreads();
    if (tid < DD) {
        float s = 0.f;
#pragma unroll
        for (int i = 0; i < 8; ++i) s += reprS[i][tid];
        feat[(size_t)row * (2 * DD) + h * DD + tid] = s / fmaxf(trueK, 1.0f);
    }
    if (tid == 0) {
        float p = 0.f;
#pragma unroll
        for (int i = 0; i < 8; ++i) p += posS[i];
        (h ? FPpos : FMpos)[row] = p;
        (h ? cntP : cntF)[row] = trueK;
    }
}

// ---------- dense body: exp row-sum over one (128-row, 384-col) tile -------
__device__ __forceinline__ void dense_body(
        int unit, char* smem,
        const __hip_bfloat16* __restrict__ Fnb,
        const __hip_bfloat16* __restrict__ Mnb,
        const __hip_bfloat16* __restrict__ Pnb,
        float* __restrict__ FMtot, float* __restrict__ FPtot) {
    __hip_bfloat16 (*Bs)[PBL] = (__hip_bfloat16(*)[PBL])smem;   // 64 x PBL
    const int bx = unit % 48, by = (unit / 48) % 16, half = unit / 768;
    const __hip_bfloat16* Bnb = half ? Pnb : Mnb;
    float* TOT = half ? FPtot : FMtot;
    const int tid = threadIdx.x;
    const int w = tid >> 6, lane = tid & 63;
    const int m = lane & 15, q = lane >> 4;
    const int rb = bx * 128 + w * 32;
    const int j0 = by * (NN / 16);                   // 384-col strip

    s16x8 a[2][4];
#pragma unroll
    for (int g = 0; g < 2; ++g)
#pragma unroll
        for (int ks = 0; ks < 4; ++ks)
            a[g][ks] = *reinterpret_cast<const s16x8*>(
                Fnb + (size_t)(rb + g * 16 + m) * DD + ks * 32 + q * 8);

    float4 s0, s1, s2, s3;
    auto issue = [&](int jc) {
        const float4* gp = reinterpret_cast<const float4*>(Bnb + (size_t)jc * DD);
        ld4_async(gp + tid,       s0);
        ld4_async(gp + 256 + tid, s1);
        ld4_async(gp + 512 + tid, s2);
        ld4_async(gp + 768 + tid, s3);
    };
    auto stash = [&](int idx, const float4& v) {
        *reinterpret_cast<float4*>(&Bs[idx >> 4][(idx & 15) * 8]) = v;
    };

    issue(j0);
    float tot[2][4] = {{0.f, 0.f, 0.f, 0.f}, {0.f, 0.f, 0.f, 0.f}};
    for (int it = 0; it < 6; ++it) {
        vm_wait0();
        __syncthreads();
        stash(tid, s0);
        stash(256 + tid, s1);
        stash(512 + tid, s2);
        stash(768 + tid, s3);
        __syncthreads();
        if (it + 1 < 6) issue(j0 + (it + 1) * 64);
#pragma unroll
        for (int t = 0; t < 4; ++t) {
            s16x8 b[4];
#pragma unroll
            for (int ks = 0; ks < 4; ++ks)
                b[ks] = *reinterpret_cast<const s16x8*>(
                    &Bs[t * 16 + m][ks * 32 + q * 8]);
#pragma unroll
            for (int g = 0; g < 2; ++g) {
                f32x4 acc = {0.f, 0.f, 0.f, 0.f};
#pragma unroll
                for (int ks = 0; ks < 4; ++ks)
                    acc = __builtin_amdgcn_mfma_f32_16x16x32_bf16(
                        a[g][ks], b[ks], acc, 0, 0, 0);
#pragma unroll
                for (int r = 0; r < 4; ++r)
                    tot[g][r] += __expf(acc[r] * INV_TAU);
            }
        }
    }
#pragma unroll
    for (int msk = 1; msk <= 8; msk <<= 1)
#pragma unroll
        for (int g = 0; g < 2; ++g)
#pragma unroll
            for (int r = 0; r < 4; ++r)
                tot[g][r] += __shfl_xor(tot[g][r], msk);
    if (m == 0)
#pragma unroll
        for (int g = 0; g < 2; ++g)
#pragma unroll
            for (int r = 0; r < 4; ++r)
                atomicAdd(&TOT[rb + g * 16 + q * 4 + r], tot[g][r]);
}

// ------- Kernel 2: co-scheduled sparse-stream + dense-MFMA -----------------
// 13824 blocks: every 9th is a dense unit (1536), the rest sparse (12288).
// Interleaving puts stream-phase and compute-phase blocks on every CU so the
// HBM pipe and the MFMA/VALU pipes stay busy simultaneously (m114 overlap).
__global__ __launch_bounds__(256) void k_main(
        const float* __restrict__ FM_adj, const float* __restrict__ FP_adj,
        const float* __restrict__ embM, const float* __restrict__ embP,
        const float* __restrict__ Fn,
        const float* __restrict__ rnM, const float* __restrict__ rnP,
        const __hip_bfloat16* __restrict__ Fnb,
        const __hip_bfloat16* __restrict__ Mnb,
        const __hip_bfloat16* __restrict__ Pnb,
        float* __restrict__ feat,
        float* __restrict__ FMpos, float* __restrict__ FPpos,
        float* __restrict__ FMtot, float* __restrict__ FPtot,
        float* __restrict__ cntF, float* __restrict__ cntP) {
    __shared__ char smem[64 * PBL * 2];              // 17408 B (union)
    const int b = blockIdx.x;
    const int u = b / 9, r = b - u * 9;
    if (r == 8)
        dense_body(u, smem, Fnb, Mnb, Pnb, FMtot, FPtot);
    else
        sparse_body(u * 8 + r, smem, FM_adj, FP_adj, embM, embP,
                    Fn, rnM, rnP, feat, FMpos, FPpos, cntF, cntP);
}

// ------- Kernel 3: MLP + softmax + loss (4 rows / 256-thread block) --------
__global__ __launch_bounds__(256) void k_mlp(
        const float* __restrict__ feat,
        const float* __restrict__ W1, const float* __restrict__ b1,
        const float* __restrict__ W2, const float* __restrict__ b2,
        const float* __restrict__ FMpos, const float* __restrict__ FPpos,
        const float* __restrict__ FMtot, const float* __restrict__ FPtot,
        const float* __restrict__ cntF, const float* __restrict__ cntP,
        float* __restrict__ out) {
    __shared__ float featS[4][2 * DD];               // 4 KB
    __shared__ float partS[2][4][DD];                // 4 KB
    __shared__ float redS[2][4][2];
    __shared__ float lossS[4];
    const int tid = threadIdx.x;
    const int cp = tid >> 7, d = tid & 127;
    const int row0 = blockIdx.x * 4;
    for (int idx = tid; idx < 4 * 2 * DD; idx += 256)
        featS[idx >> 8][idx & 255] = feat[(size_t)row0 * (2 * DD) + idx];
    __syncthreads();
    float bb = (cp == 0) ? b1[d] : 0.f;
    float acc[4];
#pragma unroll
    for (int r = 0; r < 4; ++r) acc[r] = bb;
    const int c0 = cp * 128;
    for (int c = c0; c < c0 + 128; c += 2) {
        float wA = W1[c * DD + d];
        float wB = W1[(c + 1) * DD + d];
#pragma unroll
        for (int r = 0; r < 4; ++r)
            acc[r] = fmaf(featS[r][c + 1], wB, fmaf(featS[r][c], wA, acc[r]));
    }
#pragma unroll
    for (int r = 0; r < 4; ++r) partS[cp][r][d] = acc[r];
    __syncthreads();
    if (tid < 128) {
        const int lane = tid & 63, wv = tid >> 6;
        float w20 = W2[2 * tid], w21 = W2[2 * tid + 1];
        float p0s[4], p1s[4];
#pragma unroll
        for (int r = 0; r < 4; ++r) {
            float hh = fmaxf(partS[0][r][tid] + partS[1][r][tid], 0.f);
            p0s[r] = hh * w20;
            p1s[r] = hh * w21;
        }
#pragma unroll
        for (int r = 0; r < 4; ++r)
#pragma unroll
            for (int msk = 1; msk <= 32; msk <<= 1) {
                p0s[r] += __shfl_xor(p0s[r], msk);
                p1s[r] += __shfl_xor(p1s[r], msk);
            }
        if (lane == 0)
#pragma unroll
            for (int r = 0; r < 4; ++r) {
                redS[wv][r][0] = p0s[r];
                redS[wv][r][1] = p1s[r];
            }
    }
    __syncthreads();
    if (tid < 4) {
        int row = row0 + tid;
        float z0 = redS[0][tid][0] + redS[1][tid][0] + b2[0];
        float z1 = redS[0][tid][1] + redS[1][tid][1] + b2[1];
        float mx = fmaxf(z0, z1);
        float e0 = expf(z0 - mx), e1 = expf(z1 - mx);
        float inv = 1.0f / (e0 + e1);
        float w0 = e0 * inv, w1 = e1 * inv;
        out[1 + row * 2 + 0] = w0;
        out[1 + row * 2 + 1] = w1;
        float wp = w0 * FMpos[row] + w1 * FPpos[row];
        float wn = w0 * (FMtot[row] - FMpos[row]) +
                   w1 * (FPtot[row] - FPpos[row]);
        float nei = fmaxf(cntF[row] + cntP[row], 1.0f);
        float ratio = wp / (wp + wn) / nei;
        ratio = fmaxf(ratio, 1e-10f);
        lossS[tid] = -logf(ratio);
    }
    __syncthreads();
    if (tid == 0) {
        float L = 0.f;
#pragma unroll
        for (int r = 0; r < 4; ++r) L += lossS[r];
        atomicAdd(out, L * (1.0f / NN));
    }
}

extern "C" void kernel_launch(void* const* d_in, const int* in_sizes, int n_in,
                              void* d_out, int out_size, void* d_ws, size_t ws_size,
                              hipStream_t stream) {
    const float* embF   = (const float*)d_in[0];
    const float* embM   = (const float*)d_in[1];
    const float* embP   = (const float*)d_in[2];
    const float* FM_adj = (const float*)d_in[3];
    const float* FP_adj = (const float*)d_in[4];
    const float* W1     = (const float*)d_in[5];
    const float* b1     = (const float*)d_in[6];
    const float* W2     = (const float*)d_in[7];
    const float* b2     = (const float*)d_in[8];
    float* out = (float*)d_out;

    float* ws = (float*)d_ws;
    float* FMtot = ws;                       // N  (atomic -> zeroed)
    float* FPtot = FMtot + NN;               // N  (atomic -> zeroed)
    float* FMpos = FPtot + NN;               // N
    float* FPpos = FMpos + NN;               // N
    float* cntF  = FPpos + NN;               // N
    float* cntP  = cntF + NN;                // N
    float* rnM   = cntP + NN;                // N
    float* rnP   = rnM + NN;                 // N
    float* feat  = rnP + NN;                 // N*2D
    float* Fn    = feat + (size_t)NN * 2 * DD;   // N*D fp32 normalized
    __hip_bfloat16* Fnb = (__hip_bfloat16*)(Fn + (size_t)NN * DD);
    __hip_bfloat16* Mnb = Fnb + (size_t)NN * DD;
    __hip_bfloat16* Pnb = Mnb + (size_t)NN * DD;

    hipMemsetAsync(FMtot, 0, 2 * NN * sizeof(float), stream);
    hipMemsetAsync(d_out, 0, sizeof(float), stream);

    k_normalize<<<dim3(NN / 4, 3), 256, 0, stream>>>(embF, embM, embP,
                                                     Fn, rnM, rnP,
                                                     Fnb, Mnb, Pnb);
    k_main<<<dim3(13824), 256, 0, stream>>>(FM_adj, FP_adj, embM, embP,
                                            Fn, rnM, rnP, Fnb, Mnb, Pnb,
                                            feat, FMpos, FPpos, FMtot, FPtot,
                                            cntF, cntP);
    k_mlp<<<dim3(NN / 4), 256, 0, stream>>>(feat, W1, b1, W2, b2,
                                            FMpos, FPpos, FMtot, FPtot,
                                            cntF, cntP, out);
}

// Round 14
// 369.376 us; speedup vs baseline: 1.0695x; 1.0402x over previous
//
#include <hip/hip_runtime.h>
#include <hip/hip_bf16.h>

#define NN 6144
#define DD 128
#define PBL 136         // padded LDS row stride (bf16 elems) -> balanced banks
#define INV_TAU 10.0f

typedef __attribute__((ext_vector_type(4))) float f32x4;
typedef __attribute__((ext_vector_type(8))) short s16x8;

__device__ __forceinline__ void ld4_async(const float4* p, float4& d) {
    asm volatile("global_load_dwordx4 %0, %1, off" : "=v"(d) : "v"(p));
}
__device__ __forceinline__ void vm_wait0() {
    asm volatile("s_waitcnt vmcnt(0)" ::: "memory");
}

// ---------------- Kernel 1: L2 normalize -> fp32 Fn, bf16 copies, inv-norms
__global__ void k_normalize(const float* __restrict__ embF,
                            const float* __restrict__ embM,
                            const float* __restrict__ embP,
                            float* __restrict__ Fn,
                            float* __restrict__ rnM, float* __restrict__ rnP,
                            __hip_bfloat16* __restrict__ Fnb,
                            __hip_bfloat16* __restrict__ Mnb,
                            __hip_bfloat16* __restrict__ Pnb) {
    int which = blockIdx.y;
    const float* src = which == 0 ? embF : (which == 1 ? embM : embP);
    __hip_bfloat16* dstb = which == 0 ? Fnb : (which == 1 ? Mnb : Pnb);
    int wave = threadIdx.x >> 6, lane = threadIdx.x & 63;
    int row = blockIdx.x * 4 + wave;
    float2 v = reinterpret_cast<const float2*>(src + (size_t)row * DD)[lane];
    float s = v.x * v.x + v.y * v.y;
#pragma unroll
    for (int m = 1; m <= 32; m <<= 1) s += __shfl_xor(s, m);
    float inv = 1.0f / fmaxf(sqrtf(s), 1e-12f);
    float2 o; o.x = v.x * inv; o.y = v.y * inv;
    if (which == 0)
        reinterpret_cast<float2*>(Fn + (size_t)row * DD)[lane] = o;
    if (lane == 0) {
        if (which == 1) rnM[row] = inv;
        if (which == 2) rnP[row] = inv;
    }
    __hip_bfloat162 ob;
    ob.x = __float2bfloat16(o.x);
    ob.y = __float2bfloat16(o.y);
    reinterpret_cast<__hip_bfloat162*>(dstb + (size_t)row * DD)[lane] = ob;
}

// ---------------- Kernel 1b: W1 (256x128) -> bf16 W1^T (128x256) -----------
__global__ void k_prep(const float* __restrict__ W1,
                       __hip_bfloat16* __restrict__ W1tb) {
    int n = blockIdx.x, c = threadIdx.x;          // 128 blocks x 256 threads
    W1tb[n * 256 + c] = __float2bfloat16(W1[c * DD + n]);
}

// ---------- sparse body: fused scan + gather for one (row, half) -----------
__device__ __forceinline__ void sparse_body(
        int unit, char* smem,
        const float* __restrict__ FM_adj, const float* __restrict__ FP_adj,
        const float* __restrict__ embM, const float* __restrict__ embP,
        const float* __restrict__ Fn,
        const float* __restrict__ rnM, const float* __restrict__ rnP,
        __hip_bfloat16* __restrict__ featb,
        float* __restrict__ FMpos, float* __restrict__ FPpos,
        float* __restrict__ cntF, float* __restrict__ cntP) {
    float* FnS = (float*)smem;                         // 128 f
    int (*lbufT)[5] = (int(*)[5])(smem + 512);         // 256x5 i (stride 5: banks)
    int* listS = (int*)(smem + 512 + 5120);            // 128 i
    float (*reprS)[DD] = (float(*)[DD])(smem + 512 + 5120 + 512);  // 8x128 f
    float* posS = (float*)(smem + 512 + 5120 + 512 + 4096);        // 8 f
    int* wvS = (int*)(smem + 512 + 5120 + 512 + 4096 + 32);        // 4 i
    int* Ktot = (int*)(smem + 512 + 5120 + 512 + 4096 + 32 + 16);  // 2 i

    const int row = unit >> 1, h = unit & 1;
    const float* adj  = h ? FP_adj : FM_adj;
    const float* embX = h ? embP : embM;
    const float* RN   = h ? rnP : rnM;
    const int tid = threadIdx.x, wv = tid >> 6, lane = tid & 63;

    if (tid < 32)
        reinterpret_cast<float4*>(FnS)[tid] =
            reinterpret_cast<const float4*>(Fn + (size_t)row * DD)[tid];

    // ---- phase A: scan with 6 asm-forced loads in flight ----
    const float4* rp = reinterpret_cast<const float4*>(adj + (size_t)row * NN);
    float4 v0, v1, v2, v3, v4, v5;
    ld4_async(rp + tid,        v0);
    ld4_async(rp + 256 + tid,  v1);
    ld4_async(rp + 512 + tid,  v2);
    ld4_async(rp + 768 + tid,  v3);
    ld4_async(rp + 1024 + tid, v4);
    ld4_async(rp + 1280 + tid, v5);
    vm_wait0();
    float4 vv[6] = {v0, v1, v2, v3, v4, v5};
    int mycnt = 0;
#pragma unroll
    for (int u = 0; u < 6; ++u) {
        int cb = (u * 256 + tid) * 4;
        if (vv[u].x != 0.f) { if (mycnt < 4) lbufT[tid][mycnt] = cb;     mycnt++; }
        if (vv[u].y != 0.f) { if (mycnt < 4) lbufT[tid][mycnt] = cb + 1; mycnt++; }
        if (vv[u].z != 0.f) { if (mycnt < 4) lbufT[tid][mycnt] = cb + 2; mycnt++; }
        if (vv[u].w != 0.f) { if (mycnt < 4) lbufT[tid][mycnt] = cb + 3; mycnt++; }
    }
    int cnt = mycnt < 4 ? mycnt : 4;         // P(thread>4 nnz in 24 cols) ~ 0
    int x = cnt;                             // inclusive prefix within wave
#pragma unroll
    for (int d = 1; d < 64; d <<= 1) {
        int y = __shfl_up(x, d);
        if (lane >= d) x += y;
    }
    int t = mycnt;                           // true per-wave total
#pragma unroll
    for (int msk = 1; msk <= 32; msk <<= 1) t += __shfl_xor(t, msk);
    if (tid == 0) Ktot[1] = 0;
    if (lane == 63) wvS[wv] = x;
    __syncthreads();
    if (lane == 0) atomicAdd(&Ktot[1], t);
    if (tid == 0) {
        int s = 0;
#pragma unroll
        for (int i = 0; i < 4; ++i) { int v = wvS[i]; wvS[i] = s; s += v; }
        Ktot[0] = s < 128 ? s : 128;
    }
    __syncthreads();
    int off = wvS[wv] + (x - cnt);
    for (int i = 0; i < cnt; ++i) {
        int s = off + i;
        if (s < 128) listS[s] = lbufT[tid][i];
    }
    __syncthreads();
    const int K = Ktot[0];
    const float trueK = (float)Ktot[1];

    // ---- phase B: gather (half-wave per neighbor) ----
    const int hw = tid >> 5, sl = tid & 31;
    float4 f4 = reinterpret_cast<const float4*>(FnS)[sl];
    float4 racc = {0.f, 0.f, 0.f, 0.f};
    float wsum = 0.f;
    for (int k = hw; k < K; k += 8) {
        int j = listS[k];
        float rn = RN[j];
        float4 e = reinterpret_cast<const float4*>(embX + (size_t)j * DD)[sl];
        racc.x += e.x; racc.y += e.y; racc.z += e.z; racc.w += e.w;
        float d = f4.x * e.x + f4.y * e.y + f4.z * e.z + f4.w * e.w;
#pragma unroll
        for (int msk = 1; msk <= 16; msk <<= 1) d += __shfl_xor(d, msk);
        wsum += __expf(d * rn * INV_TAU);
    }
    reinterpret_cast<float4*>(&reprS[hw][0])[sl] = racc;
    if (sl == 0) posS[hw] = wsum;
    __syncthreads();
    if (tid < DD) {
        float s = 0.f;
#pragma unroll
        for (int i = 0; i < 8; ++i) s += reprS[i][tid];
        featb[(size_t)row * (2 * DD) + h * DD + tid] =
            __float2bfloat16(s / fmaxf(trueK, 1.0f));
    }
    if (tid == 0) {
        float p = 0.f;
#pragma unroll
        for (int i = 0; i < 8; ++i) p += posS[i];
        (h ? FPpos : FMpos)[row] = p;
        (h ? cntP : cntF)[row] = trueK;
    }
}

// ---------- dense body: exp row-sum over one (128-row, 384-col) tile -------
__device__ __forceinline__ void dense_body(
        int unit, char* smem,
        const __hip_bfloat16* __restrict__ Fnb,
        const __hip_bfloat16* __restrict__ Mnb,
        const __hip_bfloat16* __restrict__ Pnb,
        float* __restrict__ FMtot, float* __restrict__ FPtot) {
    __hip_bfloat16 (*Bs)[PBL] = (__hip_bfloat16(*)[PBL])smem;   // 64 x PBL
    const int bx = unit % 48, by = (unit / 48) % 16, half = unit / 768;
    const __hip_bfloat16* Bnb = half ? Pnb : Mnb;
    float* TOT = half ? FPtot : FMtot;
    const int tid = threadIdx.x;
    const int w = tid >> 6, lane = tid & 63;
    const int m = lane & 15, q = lane >> 4;
    const int rb = bx * 128 + w * 32;
    const int j0 = by * (NN / 16);                   // 384-col strip

    s16x8 a[2][4];
#pragma unroll
    for (int g = 0; g < 2; ++g)
#pragma unroll
        for (int ks = 0; ks < 4; ++ks)
            a[g][ks] = *reinterpret_cast<const s16x8*>(
                Fnb + (size_t)(rb + g * 16 + m) * DD + ks * 32 + q * 8);

    float4 s0, s1, s2, s3;
    auto issue = [&](int jc) {
        const float4* gp = reinterpret_cast<const float4*>(Bnb + (size_t)jc * DD);
        ld4_async(gp + tid,       s0);
        ld4_async(gp + 256 + tid, s1);
        ld4_async(gp + 512 + tid, s2);
        ld4_async(gp + 768 + tid, s3);
    };
    auto stash = [&](int idx, const float4& v) {
        *reinterpret_cast<float4*>(&Bs[idx >> 4][(idx & 15) * 8]) = v;
    };

    issue(j0);
    float tot[2][4] = {{0.f, 0.f, 0.f, 0.f}, {0.f, 0.f, 0.f, 0.f}};
    for (int it = 0; it < 6; ++it) {
        vm_wait0();
        __syncthreads();
        stash(tid, s0);
        stash(256 + tid, s1);
        stash(512 + tid, s2);
        stash(768 + tid, s3);
        __syncthreads();
        if (it + 1 < 6) issue(j0 + (it + 1) * 64);
#pragma unroll
        for (int t = 0; t < 4; ++t) {
            s16x8 b[4];
#pragma unroll
            for (int ks = 0; ks < 4; ++ks)
                b[ks] = *reinterpret_cast<const s16x8*>(
                    &Bs[t * 16 + m][ks * 32 + q * 8]);
#pragma unroll
            for (int g = 0; g < 2; ++g) {
                f32x4 acc = {0.f, 0.f, 0.f, 0.f};
#pragma unroll
                for (int ks = 0; ks < 4; ++ks)
                    acc = __builtin_amdgcn_mfma_f32_16x16x32_bf16(
                        a[g][ks], b[ks], acc, 0, 0, 0);
#pragma unroll
                for (int r = 0; r < 4; ++r)
                    tot[g][r] += __expf(acc[r] * INV_TAU);
            }
        }
    }
#pragma unroll
    for (int msk = 1; msk <= 8; msk <<= 1)
#pragma unroll
        for (int g = 0; g < 2; ++g)
#pragma unroll
            for (int r = 0; r < 4; ++r)
                tot[g][r] += __shfl_xor(tot[g][r], msk);
    if (m == 0)
#pragma unroll
        for (int g = 0; g < 2; ++g)
#pragma unroll
            for (int r = 0; r < 4; ++r)
                atomicAdd(&TOT[rb + g * 16 + q * 4 + r], tot[g][r]);
}

// ------- Kernel 2: co-scheduled sparse-stream + dense-MFMA -----------------
__global__ __launch_bounds__(256) void k_main(
        const float* __restrict__ FM_adj, const float* __restrict__ FP_adj,
        const float* __restrict__ embM, const float* __restrict__ embP,
        const float* __restrict__ Fn,
        const float* __restrict__ rnM, const float* __restrict__ rnP,
        const __hip_bfloat16* __restrict__ Fnb,
        const __hip_bfloat16* __restrict__ Mnb,
        const __hip_bfloat16* __restrict__ Pnb,
        __hip_bfloat16* __restrict__ featb,
        float* __restrict__ FMpos, float* __restrict__ FPpos,
        float* __restrict__ FMtot, float* __restrict__ FPtot,
        float* __restrict__ cntF, float* __restrict__ cntP) {
    __shared__ char smem[64 * PBL * 2];              // 17408 B (union)
    const int b = blockIdx.x;
    const int u = b / 9, r = b - u * 9;
    if (r == 8)
        dense_body(u, smem, Fnb, Mnb, Pnb, FMtot, FPtot);
    else
        sparse_body(u * 8 + r, smem, FM_adj, FP_adj, embM, embP,
                    Fn, rnM, rnP, featb, FMpos, FPpos, cntF, cntP);
}

// ------- Kernel 3: MLP hidden+logit partials via MFMA ----------------------
// One wave per (16-row tile, 16-hidden tile): 8 MFMAs, relu, W2 scale,
// 16-lane reduce, one atomic pair per row. z zeroed by memset; b2 in k_loss.
__global__ __launch_bounds__(256) void k_mlp2(
        const __hip_bfloat16* __restrict__ featb,
        const __hip_bfloat16* __restrict__ W1tb,
        const float* __restrict__ b1, const float* __restrict__ W2,
        float* __restrict__ z) {
    const int tid = threadIdx.x, w = tid >> 6, lane = tid & 63;
    const int m = lane & 15, q = lane >> 4;
    const int unit = blockIdx.x * 4 + w;             // 0..3071
    const int rb = (unit >> 3) * 16, n0 = (unit & 7) * 16;
    f32x4 acc = {0.f, 0.f, 0.f, 0.f};
#pragma unroll
    for (int ks = 0; ks < 8; ++ks) {
        s16x8 a = *reinterpret_cast<const s16x8*>(
            featb + (size_t)(rb + m) * 256 + ks * 32 + q * 8);
        s16x8 b = *reinterpret_cast<const s16x8*>(
            W1tb + (size_t)(n0 + m) * 256 + ks * 32 + q * 8);
        acc = __builtin_amdgcn_mfma_f32_16x16x32_bf16(a, b, acc, 0, 0, 0);
    }
    const int n = n0 + m;
    float bias = b1[n], w20 = W2[2 * n], w21 = W2[2 * n + 1];
#pragma unroll
    for (int r = 0; r < 4; ++r) {
        float h = fmaxf(acc[r] + bias, 0.f);
        float p0 = h * w20, p1 = h * w21;
#pragma unroll
        for (int msk = 1; msk <= 8; msk <<= 1) {
            p0 += __shfl_xor(p0, msk);
            p1 += __shfl_xor(p1, msk);
        }
        if (m == 0) {
            int row = rb + q * 4 + r;
            atomicAdd(&z[2 * row], p0);
            atomicAdd(&z[2 * row + 1], p1);
        }
    }
}

// ------- Kernel 4: softmax weights + loss (one atomic per block) -----------
__global__ void k_loss(const float* __restrict__ z, const float* __restrict__ b2,
                       const float* __restrict__ FMpos, const float* __restrict__ FPpos,
                       const float* __restrict__ FMtot, const float* __restrict__ FPtot,
                       const float* __restrict__ cntF, const float* __restrict__ cntP,
                       float* __restrict__ out) {
    __shared__ float red[4];
    const int tid = threadIdx.x;
    const int lane = tid & 63, wv = tid >> 6;
    const int row = blockIdx.x * 256 + tid;
    float z0 = z[row * 2] + b2[0], z1 = z[row * 2 + 1] + b2[1];
    float mx = fmaxf(z0, z1);
    float e0 = expf(z0 - mx), e1 = expf(z1 - mx);
    float inv = 1.0f / (e0 + e1);
    float w0 = e0 * inv, w1 = e1 * inv;
    out[1 + row * 2 + 0] = w0;
    out[1 + row * 2 + 1] = w1;
    float wp = w0 * FMpos[row] + w1 * FPpos[row];
    float wn = w0 * (FMtot[row] - FMpos[row]) + w1 * (FPtot[row] - FPpos[row]);
    float nei = fmaxf(cntF[row] + cntP[row], 1.0f);
    float ratio = wp / (wp + wn) / nei;
    ratio = fmaxf(ratio, 1e-10f);
    float term = -logf(ratio);
#pragma unroll
    for (int msk = 1; msk <= 32; msk <<= 1) term += __shfl_xor(term, msk);
    if (lane == 0) red[wv] = term;
    __syncthreads();
    if (tid == 0)
        atomicAdd(out, (red[0] + red[1] + red[2] + red[3]) * (1.0f / NN));
}

extern "C" void kernel_launch(void* const* d_in, const int* in_sizes, int n_in,
                              void* d_out, int out_size, void* d_ws, size_t ws_size,
                              hipStream_t stream) {
    const float* embF   = (const float*)d_in[0];
    const float* embM   = (const float*)d_in[1];
    const float* embP   = (const float*)d_in[2];
    const float* FM_adj = (const float*)d_in[3];
    const float* FP_adj = (const float*)d_in[4];
    const float* W1     = (const float*)d_in[5];
    const float* b1     = (const float*)d_in[6];
    const float* W2     = (const float*)d_in[7];
    const float* b2     = (const float*)d_in[8];
    float* out = (float*)d_out;

    float* ws = (float*)d_ws;
    float* FMtot = ws;                       // N  (atomic -> zeroed)
    float* FPtot = FMtot + NN;               // N  (atomic -> zeroed)
    float* zbuf  = FPtot + NN;               // 2N (atomic -> zeroed)
    float* FMpos = zbuf + 2 * NN;            // N
    float* FPpos = FMpos + NN;               // N
    float* cntF  = FPpos + NN;               // N
    float* cntP  = cntF + NN;                // N
    float* rnM   = cntP + NN;                // N
    float* rnP   = rnM + NN;                 // N
    float* Fn    = rnP + NN;                 // N*D fp32 normalized
    __hip_bfloat16* Fnb = (__hip_bfloat16*)(Fn + (size_t)NN * DD);
    __hip_bfloat16* Mnb = Fnb + (size_t)NN * DD;
    __hip_bfloat16* Pnb = Mnb + (size_t)NN * DD;
    __hip_bfloat16* featb = Pnb + (size_t)NN * DD;       // N*256 bf16
    __hip_bfloat16* W1tb  = featb + (size_t)NN * 256;    // 128*256 bf16

    hipMemsetAsync(FMtot, 0, 4 * NN * sizeof(float), stream);
    hipMemsetAsync(d_out, 0, sizeof(float), stream);

    k_normalize<<<dim3(NN / 4, 3), 256, 0, stream>>>(embF, embM, embP,
                                                     Fn, rnM, rnP,
                                                     Fnb, Mnb, Pnb);
    k_prep<<<dim3(128), 256, 0, stream>>>(W1, W1tb);
    k_main<<<dim3(13824), 256, 0, stream>>>(FM_adj, FP_adj, embM, embP,
                                            Fn, rnM, rnP, Fnb, Mnb, Pnb,
                                            featb, FMpos, FPpos, FMtot, FPtot,
                                            cntF, cntP);
    k_mlp2<<<dim3(768), 256, 0, stream>>>(featb, W1tb, b1, W2, zbuf);
    k_loss<<<dim3(NN / 256), 256, 0, stream>>>(zbuf, b2, FMpos, FPpos,
                                               FMtot, FPtot, cntF, cntP, out);
}